// Round 1
// baseline (8573.811 us; speedup 1.0000x reference)
//
#include <hip/hip_runtime.h>
#include <math.h>

#define NT    2048      // B*S rows
#define S_LEN 1024
#define NH    12
#define DM    768
#define DKH   64
#define FF    3072
#define NL    12
#define VOC   50257

using short8 = __attribute__((ext_vector_type(8))) short;
using f32x4  = __attribute__((ext_vector_type(4))) float;

__device__ __forceinline__ float gelu_f(float x) {
    return 0.5f * x * (1.0f + erff(x * 0.70710678118654752f));
}

// ---- bf16 helpers (RNE round via bit trick; hi/lo split: x = hi + lo + O(2^-17 x)) ----
__device__ __forceinline__ ushort f2bf(float f) {
    unsigned u = __float_as_uint(f);
    unsigned r = (u + 0x7fffu + ((u >> 16) & 1u)) >> 16;
    return (ushort)r;
}
__device__ __forceinline__ float bf2f(ushort h) {
    return __uint_as_float(((unsigned)h) << 16);
}

// granule swizzle: LDS tile = [rows][4 granules of 8 bf16]; slot XOR spreads the
// 64B-strided fragment reads across all 8 bank-slots of a 128B line (~2-way max).
__device__ __forceinline__ int agran(int row, int kg) {
    return (row << 2) + (kg ^ ((row >> 1) & 3));
}

__device__ __forceinline__ void gl16(const void* g, void* l) {
    __builtin_amdgcn_global_load_lds(
        (const __attribute__((address_space(1))) void*)g,
        (__attribute__((address_space(3))) void*)l, 16, 0, 0);
}

// ---------------- embedding ----------------
__global__ void __launch_bounds__(256) embed_kernel(const int* __restrict__ ids,
        const float* __restrict__ tok, const float* __restrict__ pe,
        float* __restrict__ x) {
    int i   = blockIdx.x * 256 + threadIdx.x;
    int row = i / DM;
    int c   = i - row * DM;
    int s   = row & (S_LEN - 1);
    x[i] = tok[(size_t)ids[row] * DM + c] + pe[(size_t)s * DM + c];
}

// ---------------- activation split: f32 -> (hi, lo) bf16 ----------------
__global__ void __launch_bounds__(256) asplit_kernel(const float* __restrict__ s,
        ushort* __restrict__ dh, ushort* __restrict__ dl, int n4) {
    int i = blockIdx.x * 256 + threadIdx.x;
    if (i >= n4) return;
    float4 v = ((const float4*)s)[i];
    ushort4 hh, ll;
    hh.x = f2bf(v.x); ll.x = f2bf(v.x - bf2f(hh.x));
    hh.y = f2bf(v.y); ll.y = f2bf(v.y - bf2f(hh.y));
    hh.z = f2bf(v.z); ll.z = f2bf(v.z - bf2f(hh.z));
    hh.w = f2bf(v.w); ll.w = f2bf(v.w - bf2f(hh.w));
    ((ushort4*)dh)[i] = hh;
    ((ushort4*)dl)[i] = ll;
}

// ---------------- weight split+transpose: W[K][N] f32 -> Wt_hi/lo [N][K] bf16 ----------------
// one layer's 6 matrices in one launch: ids 0..2303 Wq/Wk/Wv/Wo, 2304..4607 W1, 4608..6911 W2
__global__ void __launch_bounds__(256) wsplit_layer(
        const float* __restrict__ Wq, const float* __restrict__ Wk,
        const float* __restrict__ Wv, const float* __restrict__ Wo,
        const float* __restrict__ W1, const float* __restrict__ W2,
        ushort* __restrict__ dh, ushort* __restrict__ dl) {
    int id = blockIdx.x;
    const float* src; int Kd, Nd; size_t off; int idt;
    if (id < 2304) {
        int m = id / 576; idt = id - m * 576;
        src = (m == 0) ? Wq : (m == 1) ? Wk : (m == 2) ? Wv : Wo;
        Kd = 768; Nd = 768; off = (size_t)589824 * m;
    } else if (id < 4608) {
        idt = id - 2304; src = W1; Kd = 768; Nd = 3072; off = 2359296;
    } else {
        idt = id - 4608; src = W2; Kd = 3072; Nd = 768; off = 4718592;
    }
    int tnn = Nd / 32;
    int bk = idt / tnn, bn = idt - bk * tnn;
    __shared__ float tile[32][33];
    int tr = threadIdx.x >> 5, tc = threadIdx.x & 31;
    #pragma unroll
    for (int p = 0; p < 4; ++p) {
        int r = tr + p * 8;
        tile[r][tc] = src[(size_t)(bk * 32 + r) * Nd + bn * 32 + tc];
    }
    __syncthreads();
    #pragma unroll
    for (int p = 0; p < 4; ++p) {
        int rr = tr + p * 8;
        float v = tile[tc][rr];
        ushort h  = f2bf(v);
        ushort lo = f2bf(v - bf2f(h));
        size_t o = off + (size_t)(bn * 32 + rr) * Kd + bk * 32 + tc;
        dh[o] = h; dl[o] = lo;
    }
}

__global__ void __launch_bounds__(256) wsplit_wout(const float* __restrict__ src,
        ushort* __restrict__ dh, ushort* __restrict__ dl) {
    const int tn = (VOC + 31) / 32;   // 1571
    int id = blockIdx.x;
    int bk = id / tn, bn = id - bk * tn;
    __shared__ float tile[32][33];
    int tr = threadIdx.x >> 5, tc = threadIdx.x & 31;
    #pragma unroll
    for (int p = 0; p < 4; ++p) {
        int r  = tr + p * 8;
        int gn = bn * 32 + tc;
        tile[r][tc] = (gn < VOC) ? src[(size_t)(bk * 32 + r) * VOC + gn] : 0.f;
    }
    __syncthreads();
    #pragma unroll
    for (int p = 0; p < 4; ++p) {
        int rr = tr + p * 8;
        int n  = bn * 32 + rr;
        if (n < VOC) {
            float v = tile[tc][rr];
            ushort h  = f2bf(v);
            ushort lo = f2bf(v - bf2f(h));
            size_t o = (size_t)n * DM + bk * 32 + tc;
            dh[o] = h; dl[o] = lo;
        }
    }
}

// ---------------- bf16x3 MFMA GEMM ----------------
// C[M,N] = A[M,K] @ Bt[N,K]^T via fp32 = (Ah+Al)(Bh+Bl), dropping Al*Bl.
// 128x128 tile, BK=32, 4 waves (2x2), each wave 64x64 out = 4x4 frags of 16x16x32.
// OUT: 0 = plain store (+bias,+act), 1 = split-K store to C + z*M*N (bias on z==0)
// BSPLIT: B pre-split bf16 [N][K]; else Bf fp32 [K][N] converted+transposed in-kernel
// NB: N not multiple of 128 (clamp staging rows, guard epilogue cols)
template<int OUT, bool ACT, bool BSPLIT, bool NB>
__device__ __forceinline__ void mm_body(
        const ushort* __restrict__ Ah, const ushort* __restrict__ Al,
        const ushort* __restrict__ Bth, const ushort* __restrict__ Btl,
        const float* __restrict__ Bf, const float* __restrict__ bias,
        float* __restrict__ C, int M, int N, int K, int kbeg, int kend) {
    __shared__ __align__(16) ushort sAh[128 * 32];
    __shared__ __align__(16) ushort sAl[128 * 32];
    __shared__ __align__(16) ushort sBh[128 * 32];
    __shared__ __align__(16) ushort sBl[128 * 32];

    const int t    = threadIdx.x;
    const int w    = t >> 6;
    const int lane = t & 63;
    const int q    = lane >> 4, r16 = lane & 15;
    const int m0 = blockIdx.y * 128, n0 = blockIdx.x * 128;

    // staging: granule G = r*256 + t -> row G>>2, slot G&3 holds k-group (slot ^ swz(row))
    size_t aoff[2], boff[2];
    int ldsoff[2];
    #pragma unroll
    for (int r = 0; r < 2; ++r) {
        int G  = r * 256 + t;
        int ml = G >> 2, s = G & 3;
        int kg = s ^ ((ml >> 1) & 3);
        aoff[r]   = (size_t)(m0 + ml) * K + kg * 8;
        ldsoff[r] = (r * 256 + w * 64) * 8;   // wave-uniform base; HW adds lane*16B
        if (BSPLIT) {
            int gn = n0 + ml;
            if (NB) gn = (gn < N) ? gn : (N - 1);
            boff[r] = (size_t)gn * K + kg * 8;
        }
    }

    // fragment LDS offsets (constant across k-steps)
    const int wm = (w >> 1) * 64, wn = (w & 1) * 64;
    int aro[4], bro[4];
    #pragma unroll
    for (int i = 0; i < 4; ++i) {
        aro[i] = agran(wm + i * 16 + r16, q) * 8;
        bro[i] = agran(wn + i * 16 + r16, q) * 8;
    }

    f32x4 acc[4][4];
    #pragma unroll
    for (int i = 0; i < 4; ++i)
        #pragma unroll
        for (int j = 0; j < 4; ++j) {
            f32x4 z = {0.f, 0.f, 0.f, 0.f};
            acc[i][j] = z;
        }

    for (int k0 = kbeg; k0 < kend; k0 += 32) {
        __syncthreads();    // previous compute done reading LDS
        // ---- stage A (always pre-split, direct-to-LDS DMA) ----
        #pragma unroll
        for (int r = 0; r < 2; ++r) {
            gl16(Ah + aoff[r] + k0, sAh + ldsoff[r]);
            gl16(Al + aoff[r] + k0, sAl + ldsoff[r]);
        }
        // ---- stage B ----
        if constexpr (BSPLIT) {
            #pragma unroll
            for (int r = 0; r < 2; ++r) {
                gl16(Bth + boff[r] + k0, sBh + ldsoff[r]);
                gl16(Btl + boff[r] + k0, sBl + ldsoff[r]);
            }
        } else {
            // fp32 [K][N]: column-strip per thread, convert + transposed swizzled write
            int nl = t & 127, kh = t >> 7;
            int gn = n0 + nl;
            if (NB) gn = (gn < N) ? gn : (N - 1);
            const float* bp = Bf + (size_t)(k0 + kh * 16) * N + gn;
            ushort hi[16], lo[16];
            #pragma unroll
            for (int ki = 0; ki < 16; ++ki) {
                float v = bp[(size_t)ki * N];
                hi[ki] = f2bf(v);
                lo[ki] = f2bf(v - bf2f(hi[ki]));
            }
            #pragma unroll
            for (int gs = 0; gs < 2; ++gs) {
                int kg = kh * 2 + gs;
                int gi = agran(nl, kg) * 8;
                short8 ph, pl;
                #pragma unroll
                for (int e = 0; e < 8; ++e) {
                    ph[e] = (short)hi[gs * 8 + e];
                    pl[e] = (short)lo[gs * 8 + e];
                }
                *(short8*)(sBh + gi) = ph;
                *(short8*)(sBl + gi) = pl;
            }
        }
        __syncthreads();    // drains vmcnt (gload_lds) + lgkm (ds_write)

        // ---- compute: 16 ds_read_b128 -> 48 MFMA ----
        short8 fah[4], fal[4], fbh[4], fbl[4];
        #pragma unroll
        for (int i = 0; i < 4; ++i) {
            fah[i] = *(const short8*)(sAh + aro[i]);
            fal[i] = *(const short8*)(sAl + aro[i]);
            fbh[i] = *(const short8*)(sBh + bro[i]);
            fbl[i] = *(const short8*)(sBl + bro[i]);
        }
        #pragma unroll
        for (int i = 0; i < 4; ++i)
            #pragma unroll
            for (int j = 0; j < 4; ++j) {
                acc[i][j] = __builtin_amdgcn_mfma_f32_16x16x32_bf16(fah[i], fbh[j], acc[i][j], 0, 0, 0);
                acc[i][j] = __builtin_amdgcn_mfma_f32_16x16x32_bf16(fah[i], fbl[j], acc[i][j], 0, 0, 0);
                acc[i][j] = __builtin_amdgcn_mfma_f32_16x16x32_bf16(fal[i], fbh[j], acc[i][j], 0, 0, 0);
            }
    }

    // ---- epilogue. C/D map (m89-verified): col = lane&15, row = (lane>>4)*4 + reg ----
    float* Co = C;
    if (OUT == 1) Co = C + (size_t)blockIdx.z * M * N;
    const bool addb = bias && (OUT != 1 || blockIdx.z == 0);
    #pragma unroll
    for (int i = 0; i < 4; ++i) {
        #pragma unroll
        for (int rr = 0; rr < 4; ++rr) {
            int gm = m0 + wm + i * 16 + q * 4 + rr;
            size_t rowo = (size_t)gm * N;
            #pragma unroll
            for (int j = 0; j < 4; ++j) {
                int gn = n0 + wn + j * 16 + r16;
                if (NB && gn >= N) continue;
                float v = acc[i][j][rr];
                if (addb) v += bias[gn];
                if (ACT)  v = gelu_f(v);
                Co[rowo + gn] = v;
            }
        }
    }
}

template<int OUT, bool ACT, bool BSPLIT, bool NB>
__global__ void __launch_bounds__(256, 2) mm_gen(
        const ushort* __restrict__ Ah, const ushort* __restrict__ Al,
        const ushort* __restrict__ Bth, const ushort* __restrict__ Btl,
        const float* __restrict__ Bf, const float* __restrict__ bias,
        float* __restrict__ C, int M, int N, int K, int kchunk) {
    int kb = blockIdx.z * kchunk;
    int ke = kb + kchunk; if (ke > K) ke = K;
    mm_body<OUT, ACT, BSPLIT, NB>(Ah, Al, Bth, Btl, Bf, bias, C, M, N, K, kb, ke);
}

template<bool BSPLIT>
__global__ void __launch_bounds__(256, 2) mm_qkv(
        const ushort* __restrict__ Ah, const ushort* __restrict__ Al,
        const ushort* Bh0, const ushort* Bl0, const ushort* Bh1, const ushort* Bl1,
        const ushort* Bh2, const ushort* Bl2,
        const float* Bf0, const float* Bf1, const float* Bf2,
        float* C0, float* C1, float* C2, int M, int N, int K) {
    int z = blockIdx.z;
    const ushort* Bh = (z == 0) ? Bh0 : (z == 1) ? Bh1 : Bh2;
    const ushort* Bl = (z == 0) ? Bl0 : (z == 1) ? Bl1 : Bl2;
    const float*  Bf = (z == 0) ? Bf0 : (z == 1) ? Bf1 : Bf2;
    float*        C  = (z == 0) ? C0  : (z == 1) ? C1  : C2;
    mm_body<0, false, BSPLIT, false>(Ah, Al, Bh, Bl, Bf, nullptr, C, M, N, K, 0, K);
}

// ---------------- attention (unchanged fp32 path) ----------------
__global__ void __launch_bounds__(256) attn_kernel(const float* __restrict__ qb,
        const float* __restrict__ kb, const float* __restrict__ vb,
        const int* __restrict__ mask, float* __restrict__ ctx) {
    const int qt = blockIdx.x;
    const int h  = blockIdx.y;
    const int b  = blockIdx.z;
    const int t  = threadIdx.x;
    const int q0 = qt * 16;

    __shared__ float sc[16][1028];
    __shared__ float KV[64][68];

    const int qr = t >> 4;
    const int jj = t & 15;

    float qreg[64];
    {
        const float* qp = qb + ((size_t)(b * S_LEN + q0 + qr) * DM + h * DKH);
        #pragma unroll
        for (int i = 0; i < 16; ++i) {
            float4 v = *(const float4*)(qp + i * 4);
            qreg[i*4+0] = v.x * 0.125f; qreg[i*4+1] = v.y * 0.125f;
            qreg[i*4+2] = v.z * 0.125f; qreg[i*4+3] = v.w * 0.125f;
        }
    }

    for (int kt = 0; kt < S_LEN; kt += 64) {
        __syncthreads();
        {
            int row = t >> 2, seg = t & 3;
            const float* kp = kb + ((size_t)(b * S_LEN + kt + row) * DM + h * DKH + seg * 16);
            float4 v0 = *(const float4*)(kp + 0);
            float4 v1 = *(const float4*)(kp + 4);
            float4 v2 = *(const float4*)(kp + 8);
            float4 v3 = *(const float4*)(kp + 12);
            float* kd = &KV[row][seg * 16];
            *(float4*)(kd + 0) = v0; *(float4*)(kd + 4)  = v1;
            *(float4*)(kd + 8) = v2; *(float4*)(kd + 12) = v3;
        }
        __syncthreads();
        #pragma unroll
        for (int i = 0; i < 4; ++i) {
            int k = jj + i * 16;
            float dot = 0.f;
            #pragma unroll
            for (int d = 0; d < 16; ++d) {
                float4 kv = *(const float4*)&KV[k][d * 4];
                dot += qreg[d*4+0]*kv.x + qreg[d*4+1]*kv.y
                     + qreg[d*4+2]*kv.z + qreg[d*4+3]*kv.w;
            }
            int kg = kt + k;
            if (mask[b * S_LEN + kg] == 0) dot = -1e9f;
            sc[qr][kg] = dot;
        }
    }
    __syncthreads();

    {
        float m = -3.4e38f;
        #pragma unroll
        for (int i = 0; i < 64; ++i) m = fmaxf(m, sc[qr][jj + i * 16]);
        #pragma unroll
        for (int off = 1; off < 16; off <<= 1) m = fmaxf(m, __shfl_xor(m, off, 16));
        float s = 0.f;
        #pragma unroll
        for (int i = 0; i < 64; ++i) {
            float e = __expf(sc[qr][jj + i * 16] - m);
            sc[qr][jj + i * 16] = e;
            s += e;
        }
        #pragma unroll
        for (int off = 1; off < 16; off <<= 1) s += __shfl_xor(s, off, 16);
        float inv = 1.0f / s;
        #pragma unroll
        for (int i = 0; i < 64; ++i) sc[qr][jj + i * 16] *= inv;
    }

    const int w = t >> 6;
    const int d = t & 63;
    float a0 = 0.f, a1 = 0.f, a2 = 0.f, a3 = 0.f;
    for (int kt = 0; kt < S_LEN; kt += 64) {
        __syncthreads();
        {
            int row = t >> 2, seg = t & 3;
            const float* vp = vb + ((size_t)(b * S_LEN + kt + row) * DM + h * DKH + seg * 16);
            float4 v0 = *(const float4*)(vp + 0);
            float4 v1 = *(const float4*)(vp + 4);
            float4 v2 = *(const float4*)(vp + 8);
            float4 v3 = *(const float4*)(vp + 12);
            float* vd = &KV[row][seg * 16];
            *(float4*)(vd + 0) = v0; *(float4*)(vd + 4)  = v1;
            *(float4*)(vd + 8) = v2; *(float4*)(vd + 12) = v3;
        }
        __syncthreads();
        #pragma unroll
        for (int kk = 0; kk < 64; kk += 4) {
            float v0 = KV[kk+0][d], v1 = KV[kk+1][d], v2 = KV[kk+2][d], v3 = KV[kk+3][d];
            float4 p;
            p = *(const float4*)&sc[w*4+0][kt+kk]; a0 += p.x*v0 + p.y*v1 + p.z*v2 + p.w*v3;
            p = *(const float4*)&sc[w*4+1][kt+kk]; a1 += p.x*v0 + p.y*v1 + p.z*v2 + p.w*v3;
            p = *(const float4*)&sc[w*4+2][kt+kk]; a2 += p.x*v0 + p.y*v1 + p.z*v2 + p.w*v3;
            p = *(const float4*)&sc[w*4+3][kt+kk]; a3 += p.x*v0 + p.y*v1 + p.z*v2 + p.w*v3;
        }
    }
    size_t obase = (size_t)(b * S_LEN + q0 + w * 4) * DM + h * DKH + d;
    ctx[obase + 0 * DM] = a0;
    ctx[obase + 1 * DM] = a1;
    ctx[obase + 2 * DM] = a2;
    ctx[obase + 3 * DM] = a3;
}

// ---------------- residual(+nres split-K partials) + LayerNorm, in place on x ----------------
__global__ void __launch_bounds__(256) ln_kernel(float* __restrict__ x,
        const float* __restrict__ res, int nres,
        const float* __restrict__ g, const float* __restrict__ b) {
    const int row = blockIdx.x;
    const int t   = threadIdx.x;
    const size_t base = (size_t)row * DM;
    const size_t CHs  = (size_t)NT * DM;
    float v[3];
    #pragma unroll
    for (int i = 0; i < 3; ++i) {
        int c = t + i * 256;
        float s = x[base + c];
        for (int r = 0; r < nres; ++r) s += res[(size_t)r * CHs + base + c];
        v[i] = s;
    }
    float s  = v[0] + v[1] + v[2];
    float s2 = v[0]*v[0] + v[1]*v[1] + v[2]*v[2];
    #pragma unroll
    for (int off = 1; off < 64; off <<= 1) {
        s  += __shfl_xor(s,  off);
        s2 += __shfl_xor(s2, off);
    }
    __shared__ float red[8];
    int w = t >> 6;
    if ((t & 63) == 0) { red[w] = s; red[w + 4] = s2; }
    __syncthreads();
    s  = red[0] + red[1] + red[2] + red[3];
    s2 = red[4] + red[5] + red[6] + red[7];
    const float mean = s * (1.0f / DM);
    const float var  = s2 * (1.0f / DM) - mean * mean;
    const float rstd = rsqrtf(var + 1e-5f);
    #pragma unroll
    for (int i = 0; i < 3; ++i) {
        int c = t + i * 256;
        x[base + c] = (v[i] - mean) * rstd * g[c] + b[c];
    }
}

// ---------------- driver ----------------
extern "C" void kernel_launch(void* const* d_in, const int* in_sizes, int n_in,
                              void* d_out, int out_size, void* d_ws, size_t ws_size,
                              hipStream_t stream) {
    (void)in_sizes; (void)n_in; (void)out_size;
    const int*   ids  = (const int*)  d_in[0];
    const int*   amsk = (const int*)  d_in[1];
    const float* tok  = (const float*)d_in[2];
    const float* pe   = (const float*)d_in[3];
    const float* Wq   = (const float*)d_in[4];
    const float* Wk   = (const float*)d_in[5];
    const float* Wv   = (const float*)d_in[6];
    const float* Wo   = (const float*)d_in[7];
    const float* ln1g = (const float*)d_in[8];
    const float* ln1b = (const float*)d_in[9];
    const float* ln2g = (const float*)d_in[10];
    const float* ln2b = (const float*)d_in[11];
    const float* W1   = (const float*)d_in[12];
    const float* b1   = (const float*)d_in[13];
    const float* W2   = (const float*)d_in[14];
    const float* b2   = (const float*)d_in[15];
    const float* lnfg = (const float*)d_in[16];
    const float* lnfb = (const float*)d_in[17];
    const float* Wout = (const float*)d_in[18];
    const float* bout = (const float*)d_in[19];
    float* out = (float*)d_out;

    float* ws = (float*)d_ws;
    const size_t CH = (size_t)NT * DM;      // 1,572,864 floats
    float* x  = ws;
    float* qb = ws + 1 * CH;                // also split-K partial base P, also h fp32
    float* kb = ws + 2 * CH;
    float* vb = ws + 3 * CH;
    float* cx = ws + 4 * CH;
    float* P  = qb;                          // 4 contiguous CH buffers: qb,kb,vb,cx
    float* hb = qb;                          // W1 output fp32, NT*FF = 4*CH
    // bf16 hi/lo activation pair (NT*FF each) — replaces old fp32 hb: base = 62.9 MB,
    // identical to the previously-verified kernel's workspace usage.
    ushort* act_h = (ushort*)(ws + 6 * CH);
    ushort* act_l = act_h + (size_t)NT * FF;

    const size_t DD   = (size_t)DM * DM;          // 589,824
    const size_t DMFF = (size_t)DM * FF;          // 2,359,296
    const size_t BASE  = 6 * CH * sizeof(float) + (size_t)NT * FF * 4;  // 62,914,560 B
    const size_t WELEM = 4 * DD + 2 * DMFF;       // 7,077,888 per-layer weight elems
    const size_t WBUFB = WELEM * 4;               // hi+lo bf16: 28,311,552 B
    const size_t WOUTE = (size_t)DM * VOC;        // 38,597,376
    const size_t WOUTB = WOUTE * 4;               // 154,389,504 B

    ushort* wb_h = (ushort*)((char*)d_ws + BASE);
    ushort* wb_l = wb_h + WELEM;
    ushort* wo_h = (ushort*)((char*)d_ws + BASE + WBUFB);
    ushort* wo_l = wo_h + WOUTE;
    const bool sW  = ws_size >= BASE + WBUFB;           // pre-split layer weights
    const bool sWo = ws_size >= BASE + WBUFB + WOUTB;   // pre-split Wout too

    const int g4ch = (int)(CH / 4);            // 393,216 -> 1536 blocks
    const int g4ff = (int)((size_t)NT * FF / 4); // 1,572,864 -> 6144 blocks

    embed_kernel<<<NT * DM / 256, 256, 0, stream>>>(ids, tok, pe, x);
    if (sWo)
        wsplit_wout<<<24 * ((VOC + 31) / 32), 256, 0, stream>>>(Wout, wo_h, wo_l);

    for (int l = 0; l < NL; ++l) {
        if (sW)
            wsplit_layer<<<6912, 256, 0, stream>>>(
                Wq + l * DD, Wk + l * DD, Wv + l * DD, Wo + l * DD,
                W1 + l * DMFF, W2 + l * DMFF, wb_h, wb_l);

        // ---- QKV ----
        asplit_kernel<<<(g4ch + 255) / 256, 256, 0, stream>>>(x, act_h, act_l, g4ch);
        if (sW)
            mm_qkv<true><<<dim3(DM / 128, NT / 128, 3), 256, 0, stream>>>(
                act_h, act_l,
                wb_h + 0,      wb_l + 0,
                wb_h + DD,     wb_l + DD,
                wb_h + 2 * DD, wb_l + 2 * DD,
                nullptr, nullptr, nullptr, qb, kb, vb, NT, DM, DM);
        else
            mm_qkv<false><<<dim3(DM / 128, NT / 128, 3), 256, 0, stream>>>(
                act_h, act_l,
                nullptr, nullptr, nullptr, nullptr, nullptr, nullptr,
                Wq + l * DD, Wk + l * DD, Wv + l * DD, qb, kb, vb, NT, DM, DM);

        attn_kernel<<<dim3(S_LEN / 16, NH, 2), 256, 0, stream>>>(qb, kb, vb, amsk, cx);

        // ---- Wo (split-K=4 into P[0..3]) ----
        asplit_kernel<<<(g4ch + 255) / 256, 256, 0, stream>>>(cx, act_h, act_l, g4ch);
        if (sW)
            mm_gen<1, false, true, false><<<dim3(DM / 128, NT / 128, 4), 256, 0, stream>>>(
                act_h, act_l, wb_h + 3 * DD, wb_l + 3 * DD, nullptr, nullptr,
                P, NT, DM, DM, DM / 4);
        else
            mm_gen<1, false, false, false><<<dim3(DM / 128, NT / 128, 4), 256, 0, stream>>>(
                act_h, act_l, nullptr, nullptr, Wo + l * DD, nullptr,
                P, NT, DM, DM, DM / 4);
        ln_kernel<<<NT, 256, 0, stream>>>(x, P, 4, ln1g + l * DM, ln1b + l * DM);

        // ---- FF up (gelu) ----
        asplit_kernel<<<(g4ch + 255) / 256, 256, 0, stream>>>(x, act_h, act_l, g4ch);
        if (sW)
            mm_gen<0, true, true, false><<<dim3(FF / 128, NT / 128, 1), 256, 0, stream>>>(
                act_h, act_l, wb_h + 4 * DD, wb_l + 4 * DD, nullptr, b1 + (size_t)l * FF,
                hb, NT, FF, DM, DM);
        else
            mm_gen<0, true, false, false><<<dim3(FF / 128, NT / 128, 1), 256, 0, stream>>>(
                act_h, act_l, nullptr, nullptr, W1 + l * DMFF, b1 + (size_t)l * FF,
                hb, NT, FF, DM, DM);

        // ---- FF down (split-K=4 into P[0..3]) ----
        asplit_kernel<<<(g4ff + 255) / 256, 256, 0, stream>>>(hb, act_h, act_l, g4ff);
        if (sW)
            mm_gen<1, false, true, false><<<dim3(DM / 128, NT / 128, 4), 256, 0, stream>>>(
                act_h, act_l, wb_h + 4 * DD + DMFF, wb_l + 4 * DD + DMFF, nullptr,
                b2 + (size_t)l * DM, P, NT, DM, FF, FF / 4);
        else
            mm_gen<1, false, false, false><<<dim3(DM / 128, NT / 128, 4), 256, 0, stream>>>(
                act_h, act_l, nullptr, nullptr, W2 + l * DMFF,
                b2 + (size_t)l * DM, P, NT, DM, FF, FF / 4);
        ln_kernel<<<NT, 256, 0, stream>>>(x, P, 4, ln2g + l * DM, ln2b + l * DM);
    }

    ln_kernel<<<NT, 256, 0, stream>>>(x, nullptr, 0, lnfg, lnfb);
    asplit_kernel<<<(g4ch + 255) / 256, 256, 0, stream>>>(x, act_h, act_l, g4ch);
    if (sWo)
        mm_gen<0, false, true, true><<<dim3((VOC + 127) / 128, NT / 128, 1), 256, 0, stream>>>(
            act_h, act_l, wo_h, wo_l, nullptr, bout, out, NT, VOC, DM, DM);
    else
        mm_gen<0, false, false, true><<<dim3((VOC + 127) / 128, NT / 128, 1), 256, 0, stream>>>(
            act_h, act_l, nullptr, nullptr, Wout, bout, out, NT, VOC, DM, DM);
}